// Round 2
// baseline (1102.608 us; speedup 1.0000x reference)
//
#include <hip/hip_runtime.h>

#define NB 2048
#define NT 128

// permutation of the interleaved h layout: LDS pos p holds h_{JP(p)}
#define JP(p) ((((p) & 1) ? 32 : 0) + ((p) >> 1))

// ---------------------------------------------------------------------------
// Kernel 1: action-latent MLP  (B*T, 8) -> relu(64) -> (B*T, 16), into d_ws
// ---------------------------------------------------------------------------
__global__ __launch_bounds__(256, 4) void acl_kernel(
    const float* __restrict__ acs, const float* __restrict__ acW0,
    const float* __restrict__ acb0, const float* __restrict__ acW1,
    const float* __restrict__ acb1, float* __restrict__ aclout)
{
    __shared__ float sW0[64 * 8];
    __shared__ float sW1[16 * 64];
    __shared__ float sB0[64];
    __shared__ float sB1[16];
    const int tid = threadIdx.x;
    for (int i = tid; i < 64 * 8; i += 256) sW0[i] = acW0[i];
    for (int i = tid; i < 16 * 64; i += 256) sW1[i] = acW1[i];
    if (tid < 64) sB0[tid] = acb0[tid];
    if (tid < 16) sB1[tid] = acb1[tid];
    __syncthreads();

    const int row = blockIdx.x * 256 + tid;
    const float4 x0 = *(const float4*)&acs[row * 8];
    const float4 x1 = *(const float4*)&acs[row * 8 + 4];

    float o[16];
    #pragma unroll
    for (int m = 0; m < 16; ++m) o[m] = sB1[m];

    #pragma unroll
    for (int jc = 0; jc < 16; ++jc) {
        float hq[4];
        #pragma unroll
        for (int u = 0; u < 4; ++u) {
            const int j = jc * 4 + u;
            const float4 wa = *(const float4*)&sW0[j * 8];
            const float4 wb = *(const float4*)&sW0[j * 8 + 4];
            float hv = sB0[j];
            hv = fmaf(x0.x, wa.x, hv); hv = fmaf(x0.y, wa.y, hv);
            hv = fmaf(x0.z, wa.z, hv); hv = fmaf(x0.w, wa.w, hv);
            hv = fmaf(x1.x, wb.x, hv); hv = fmaf(x1.y, wb.y, hv);
            hv = fmaf(x1.z, wb.z, hv); hv = fmaf(x1.w, wb.w, hv);
            hq[u] = fmaxf(hv, 0.f);
        }
        #pragma unroll
        for (int m = 0; m < 16; ++m) {
            const float4 wv = *(const float4*)&sW1[m * 64 + jc * 4];
            o[m] = fmaf(hq[0], wv.x, o[m]);
            o[m] = fmaf(hq[1], wv.y, o[m]);
            o[m] = fmaf(hq[2], wv.z, o[m]);
            o[m] = fmaf(hq[3], wv.w, o[m]);
        }
    }
    float4* op = (float4*)&aclout[row * 16];
    op[0] = make_float4(o[0],  o[1],  o[2],  o[3]);
    op[1] = make_float4(o[4],  o[5],  o[6],  o[7]);
    op[2] = make_float4(o[8],  o[9],  o[10], o[11]);
    op[3] = make_float4(o[12], o[13], o[14], o[15]);
}

// ---------------------------------------------------------------------------
// Kernel 2 v4: 2 batch elements per wave, half-wave (32 lanes) per element.
//  - lane (e, m): element e = tid>>5 within block, state component m.
//  - layer 1: lane computes h rows m and m+32 (both dynW0 rows in VGPRs).
//  - layer 2: lane computes the FULL o_m (all-64 dynW1 row in VGPRs) -> no
//    shfl reduce, no pair-lane redundancy.
//  - h stored interleaved (pos 2i -> h_i, 2i+1 -> h_{32+i}) so the per-lane
//    {h_m,h_{m+32}} pair is ONE ds_write_b64; gather order compensated by
//    compile-time-permuted w1row indexing (JP).
//  - DS instrs/feval: 26 per 2 elements (vs 38 in v2); broadcasts serve both
//    elements per instruction. Grid: 1024 waves (1/SIMD), launch_bounds(256,1).
// ---------------------------------------------------------------------------
__global__ __launch_bounds__(256, 1) void ode_kernel(
    const float* __restrict__ encW0, const float* __restrict__ encb0,
    const float* __restrict__ encW1, const float* __restrict__ encb1,
    const float* __restrict__ dynW0, const float* __restrict__ dynb0,
    const float* __restrict__ dynW1, const float* __restrict__ dynb1,
    const float* __restrict__ decW0, const float* __restrict__ decb0,
    const float* __restrict__ decW1, const float* __restrict__ decb1,
    const float* __restrict__ ob,    const float* __restrict__ times,
    const float* __restrict__ aclws, float* __restrict__ out)
{
    __shared__ float sEncW0T[64 * 64];   // [k][j]
    __shared__ float sEncW1P[64 * 32];   // [p][m], p = interleaved-h position
    __shared__ float sDecW0T[32 * 64];   // [k][j]
    __shared__ float sDecW1P[64 * 64];   // [p][n]
    __shared__ float obuf[512];          // 8 elements x 64
    __shared__ float tbuf[1024];         // 8 elements x 128
    __shared__ float xb[256];            // 8 elements x 32 (broadcast buffer)
    __shared__ float hbi[512];           // 8 elements x 64, interleaved layout

    const int tid   = threadIdx.x;
    const int lane  = tid & 63;
    const int m     = lane & 31;
    const int eb    = tid >> 5;               // element index in block, 0..7
    const int bu    = blockIdx.x * 8 + eb;    // per-lane batch element
    const int xbase = eb * 32;
    const int hbase = eb * 64;

    // ---- stage weights (transposed / permuted) + per-block inputs into LDS
    for (int i = tid; i < 64 * 64; i += 256) { int r = i >> 6, c = i & 63; sEncW0T[c * 64 + r] = encW0[i]; }
    for (int i = tid; i < 64 * 32; i += 256) { int p = i >> 5, mm = i & 31; sEncW1P[i] = encW1[mm * 64 + JP(p)]; }
    for (int i = tid; i < 64 * 32; i += 256) { sDecW0T[(i & 31) * 64 + (i >> 5)] = decW0[i]; }
    for (int i = tid; i < 64 * 64; i += 256) { int p = i >> 6, n = i & 63; sDecW1P[i] = decW1[n * 64 + JP(p)]; }
    obuf[tid]       = ob[blockIdx.x * 512 + tid];
    obuf[tid + 256] = ob[blockIdx.x * 512 + tid + 256];
    #pragma unroll
    for (int q = 0; q < 4; ++q) tbuf[tid + q * 256] = times[blockIdx.x * 1024 + tid + q * 256];

    // ---- dyn weights -> registers (per lane: rows m and m+32 of dynW0,
    //      full row m of dynW1, acl-columns of both dynW0 rows)
    float w0a[32], w0b[32], wa0[16], wa1[16], w1row[64];
    #pragma unroll
    for (int q = 0; q < 8; ++q) *(float4*)&w0a[q * 4] = *(const float4*)&dynW0[m * 48 + q * 4];
    #pragma unroll
    for (int q = 0; q < 8; ++q) *(float4*)&w0b[q * 4] = *(const float4*)&dynW0[(m + 32) * 48 + q * 4];
    #pragma unroll
    for (int q = 0; q < 4; ++q) *(float4*)&wa0[q * 4] = *(const float4*)&dynW0[m * 48 + 32 + q * 4];
    #pragma unroll
    for (int q = 0; q < 4; ++q) *(float4*)&wa1[q * 4] = *(const float4*)&dynW0[(m + 32) * 48 + 32 + q * 4];
    #pragma unroll
    for (int q = 0; q < 16; ++q) *(float4*)&w1row[q * 4] = *(const float4*)&dynW1[m * 64 + q * 4];
    const float b0r0 = dynb0[m], b0r1 = dynb0[m + 32], b1r = dynb1[m];
    const float dB00 = decb0[m], dB01 = decb0[m + 32];
    const float dB10 = decb1[m], dB11 = decb1[m + 32];

    __syncthreads();

    // ---- f(x): x per-lane (component m of this lane's element)
    auto feval = [&](float x, float hp0, float hp1) -> float {
        __builtin_amdgcn_wave_barrier();
        xb[tid] = x;
        __builtin_amdgcn_wave_barrier();
        float a0 = hp0, a1 = 0.f, a2 = 0.f, a3 = 0.f;
        float e0 = hp1, e1 = 0.f, e2 = 0.f, e3 = 0.f;
        #pragma unroll
        for (int q = 0; q < 8; ++q) {
            const float4 xv = *(const float4*)&xb[xbase + q * 4];
            a0 = fmaf(xv.x, w0a[q * 4 + 0], a0); a1 = fmaf(xv.y, w0a[q * 4 + 1], a1);
            a2 = fmaf(xv.z, w0a[q * 4 + 2], a2); a3 = fmaf(xv.w, w0a[q * 4 + 3], a3);
            e0 = fmaf(xv.x, w0b[q * 4 + 0], e0); e1 = fmaf(xv.y, w0b[q * 4 + 1], e1);
            e2 = fmaf(xv.z, w0b[q * 4 + 2], e2); e3 = fmaf(xv.w, w0b[q * 4 + 3], e3);
        }
        const float h0 = fmaxf((a0 + a1) + (a2 + a3), 0.f);
        const float h1 = fmaxf((e0 + e1) + (e2 + e3), 0.f);
        __builtin_amdgcn_wave_barrier();
        *(float2*)&hbi[hbase + 2 * m] = make_float2(h0, h1);
        __builtin_amdgcn_wave_barrier();
        float c0 = 0.f, c1 = 0.f, c2 = 0.f, c3 = 0.f;
        #pragma unroll
        for (int q = 0; q < 16; ++q) {
            const float4 hv = *(const float4*)&hbi[hbase + q * 4];
            c0 = fmaf(hv.x, w1row[JP(q * 4 + 0)], c0);
            c1 = fmaf(hv.y, w1row[JP(q * 4 + 1)], c1);
            c2 = fmaf(hv.z, w1row[JP(q * 4 + 2)], c2);
            c3 = fmaf(hv.w, w1row[JP(q * 4 + 3)], c3);
        }
        return (c0 + c1) + (c2 + c3) + b1r;
    };

    auto decode_store = [&](float yv, int t) {
        __builtin_amdgcn_wave_barrier();
        xb[tid] = yv;
        __builtin_amdgcn_wave_barrier();
        float a0 = dB00, a1 = 0.f, a2 = 0.f, a3 = 0.f;
        float e0 = dB01, e1 = 0.f, e2 = 0.f, e3 = 0.f;
        #pragma unroll
        for (int q = 0; q < 8; ++q) {
            const float4 xv = *(const float4*)&xb[xbase + q * 4];
            a0 = fmaf(xv.x, sDecW0T[(q * 4 + 0) * 64 + m], a0);
            a1 = fmaf(xv.y, sDecW0T[(q * 4 + 1) * 64 + m], a1);
            a2 = fmaf(xv.z, sDecW0T[(q * 4 + 2) * 64 + m], a2);
            a3 = fmaf(xv.w, sDecW0T[(q * 4 + 3) * 64 + m], a3);
            e0 = fmaf(xv.x, sDecW0T[(q * 4 + 0) * 64 + m + 32], e0);
            e1 = fmaf(xv.y, sDecW0T[(q * 4 + 1) * 64 + m + 32], e1);
            e2 = fmaf(xv.z, sDecW0T[(q * 4 + 2) * 64 + m + 32], e2);
            e3 = fmaf(xv.w, sDecW0T[(q * 4 + 3) * 64 + m + 32], e3);
        }
        const float h0 = fmaxf((a0 + a1) + (a2 + a3), 0.f);
        const float h1 = fmaxf((e0 + e1) + (e2 + e3), 0.f);
        __builtin_amdgcn_wave_barrier();
        *(float2*)&hbi[hbase + 2 * m] = make_float2(h0, h1);
        __builtin_amdgcn_wave_barrier();
        float o0 = dB10, o1 = 0.f, o2 = 0.f, o3 = 0.f;
        float p0 = dB11, p1 = 0.f, p2 = 0.f, p3 = 0.f;
        #pragma unroll
        for (int q = 0; q < 16; ++q) {
            const float4 hv = *(const float4*)&hbi[hbase + q * 4];
            o0 = fmaf(hv.x, sDecW1P[(q * 4 + 0) * 64 + m], o0);
            o1 = fmaf(hv.y, sDecW1P[(q * 4 + 1) * 64 + m], o1);
            o2 = fmaf(hv.z, sDecW1P[(q * 4 + 2) * 64 + m], o2);
            o3 = fmaf(hv.w, sDecW1P[(q * 4 + 3) * 64 + m], o3);
            p0 = fmaf(hv.x, sDecW1P[(q * 4 + 0) * 64 + m + 32], p0);
            p1 = fmaf(hv.y, sDecW1P[(q * 4 + 1) * 64 + m + 32], p1);
            p2 = fmaf(hv.z, sDecW1P[(q * 4 + 2) * 64 + m + 32], p2);
            p3 = fmaf(hv.w, sDecW1P[(q * 4 + 3) * 64 + m + 32], p3);
        }
        const int base = (bu * NT + t) * 64;
        out[base + m]      = (o0 + o1) + (o2 + o3);
        out[base + m + 32] = (p0 + p1) + (p2 + p3);
    };

    // ---- encoder: ob(64) -> relu(64) -> y(32); lane ends with y_m
    float y;
    {
        const int obase = eb * 64;
        float a0 = encb0[m], a1 = 0.f, a2 = 0.f, a3 = 0.f;
        float e0 = encb0[m + 32], e1 = 0.f, e2 = 0.f, e3 = 0.f;
        #pragma unroll
        for (int q = 0; q < 16; ++q) {
            const float4 xv = *(const float4*)&obuf[obase + q * 4];
            a0 = fmaf(xv.x, sEncW0T[(q * 4 + 0) * 64 + m], a0);
            a1 = fmaf(xv.y, sEncW0T[(q * 4 + 1) * 64 + m], a1);
            a2 = fmaf(xv.z, sEncW0T[(q * 4 + 2) * 64 + m], a2);
            a3 = fmaf(xv.w, sEncW0T[(q * 4 + 3) * 64 + m], a3);
            e0 = fmaf(xv.x, sEncW0T[(q * 4 + 0) * 64 + m + 32], e0);
            e1 = fmaf(xv.y, sEncW0T[(q * 4 + 1) * 64 + m + 32], e1);
            e2 = fmaf(xv.z, sEncW0T[(q * 4 + 2) * 64 + m + 32], e2);
            e3 = fmaf(xv.w, sEncW0T[(q * 4 + 3) * 64 + m + 32], e3);
        }
        const float h0 = fmaxf((a0 + a1) + (a2 + a3), 0.f);
        const float h1 = fmaxf((e0 + e1) + (e2 + e3), 0.f);
        __builtin_amdgcn_wave_barrier();
        *(float2*)&hbi[hbase + 2 * m] = make_float2(h0, h1);
        __builtin_amdgcn_wave_barrier();
        float c0 = encb1[m], c1 = 0.f, c2 = 0.f, c3 = 0.f;
        #pragma unroll
        for (int q = 0; q < 16; ++q) {
            const float4 hv = *(const float4*)&hbi[hbase + q * 4];
            c0 = fmaf(hv.x, sEncW1P[(q * 4 + 0) * 32 + m], c0);
            c1 = fmaf(hv.y, sEncW1P[(q * 4 + 1) * 32 + m], c1);
            c2 = fmaf(hv.z, sEncW1P[(q * 4 + 2) * 32 + m], c2);
            c3 = fmaf(hv.w, sEncW1P[(q * 4 + 3) * 32 + m], c3);
        }
        y = (c0 + c1) + (c2 + c3);
    }

    // per-lane acl partials for dynW0 rows m and m+32
    auto acl_part2 = [&](const float* __restrict__ ap, float& r0, float& r1) {
        const float4 a0 = *(const float4*)&ap[0];
        const float4 a1 = *(const float4*)&ap[4];
        const float4 a2 = *(const float4*)&ap[8];
        const float4 a3 = *(const float4*)&ap[12];
        float s0 = 0.f, s1 = 0.f;
        s0 = fmaf(a0.x, wa0[0],  s0); s1 = fmaf(a0.y, wa0[1],  s1);
        s0 = fmaf(a0.z, wa0[2],  s0); s1 = fmaf(a0.w, wa0[3],  s1);
        s0 = fmaf(a1.x, wa0[4],  s0); s1 = fmaf(a1.y, wa0[5],  s1);
        s0 = fmaf(a1.z, wa0[6],  s0); s1 = fmaf(a1.w, wa0[7],  s1);
        s0 = fmaf(a2.x, wa0[8],  s0); s1 = fmaf(a2.y, wa0[9],  s1);
        s0 = fmaf(a2.z, wa0[10], s0); s1 = fmaf(a2.w, wa0[11], s1);
        s0 = fmaf(a3.x, wa0[12], s0); s1 = fmaf(a3.y, wa0[13], s1);
        s0 = fmaf(a3.z, wa0[14], s0); s1 = fmaf(a3.w, wa0[15], s1);
        r0 = s0 + s1;
        float u0 = 0.f, u1 = 0.f;
        u0 = fmaf(a0.x, wa1[0],  u0); u1 = fmaf(a0.y, wa1[1],  u1);
        u0 = fmaf(a0.z, wa1[2],  u0); u1 = fmaf(a0.w, wa1[3],  u1);
        u0 = fmaf(a1.x, wa1[4],  u0); u1 = fmaf(a1.y, wa1[5],  u1);
        u0 = fmaf(a1.z, wa1[6],  u0); u1 = fmaf(a1.w, wa1[7],  u1);
        u0 = fmaf(a2.x, wa1[8],  u0); u1 = fmaf(a2.y, wa1[9],  u1);
        u0 = fmaf(a2.z, wa1[10], u0); u1 = fmaf(a2.w, wa1[11], u1);
        u0 = fmaf(a3.x, wa1[12], u0); u1 = fmaf(a3.y, wa1[13], u1);
        u0 = fmaf(a3.z, wa1[14], u0); u1 = fmaf(a3.w, wa1[15], u1);
        r1 = u0 + u1;
    };

    float aC0, aC1;
    acl_part2(aclws + (size_t)(bu * NT) * 16, aC0, aC1);
    decode_store(y, 0);

    for (int i = 0; i < NT - 1; ++i) {
        const float t0v = tbuf[eb * 128 + i];
        const float t1v = tbuf[eb * 128 + i + 1];
        const float hh  = (t1v - t0v) * 0.5f;                       // /K, K=2
        float aN0, aN1;
        acl_part2(aclws + (size_t)(bu * NT + i + 1) * 16, aN0, aN1);

        #pragma unroll 1
        for (int sub = 0; sub < 2; ++sub) {
            const float tsub  = t0v + (float)sub * hh;
            // stage-6 time fl(tsub+hh): matches reference searchsorted('right')
            const bool  swap6 = (tsub + hh >= t1v);
            const float hpC0 = b0r0 + aC0;
            const float hpC1 = b0r1 + aC1;
            const float hp60 = b0r0 + (swap6 ? aN0 : aC0);
            const float hp61 = b0r1 + (swap6 ? aN1 : aC1);

            const float k1 = feval(y, hpC0, hpC1);
            const float k2 = feval(fmaf(hh, 0.2f * k1, y), hpC0, hpC1);
            const float k3 = feval(fmaf(hh, 0.075f * k1 + 0.225f * k2, y), hpC0, hpC1);
            const float k4 = feval(fmaf(hh,
                (float)(44.0/45.0)*k1 + (float)(-56.0/15.0)*k2 + (float)(32.0/9.0)*k3, y),
                hpC0, hpC1);
            const float k5 = feval(fmaf(hh,
                (float)(19372.0/6561.0)*k1 + (float)(-25360.0/2187.0)*k2
              + (float)(64448.0/6561.0)*k3 + (float)(-212.0/729.0)*k4, y),
                hpC0, hpC1);
            const float k6 = feval(fmaf(hh,
                (float)(9017.0/3168.0)*k1 + (float)(-355.0/33.0)*k2
              + (float)(46732.0/5247.0)*k3 + (float)(49.0/176.0)*k4
              + (float)(-5103.0/18656.0)*k5, y),
                hp60, hp61);
            y = fmaf(hh,
                (float)(35.0/384.0)*k1 + (float)(500.0/1113.0)*k3
              + (float)(125.0/192.0)*k4 + (float)(-2187.0/6784.0)*k5
              + (float)(11.0/84.0)*k6, y);
        }
        aC0 = aN0; aC1 = aN1;
        decode_store(y, i + 1);
    }
}

extern "C" void kernel_launch(void* const* d_in, const int* in_sizes, int n_in,
                              void* d_out, int out_size, void* d_ws, size_t ws_size,
                              hipStream_t stream)
{
    const float* encW0 = (const float*)d_in[0];
    const float* encb0 = (const float*)d_in[1];
    const float* encW1 = (const float*)d_in[2];
    const float* encb1 = (const float*)d_in[3];
    const float* acW0  = (const float*)d_in[4];
    const float* acb0  = (const float*)d_in[5];
    const float* acW1  = (const float*)d_in[6];
    const float* acb1  = (const float*)d_in[7];
    const float* dynW0 = (const float*)d_in[8];
    const float* dynb0 = (const float*)d_in[9];
    const float* dynW1 = (const float*)d_in[10];
    const float* dynb1 = (const float*)d_in[11];
    const float* decW0 = (const float*)d_in[12];
    const float* decb0 = (const float*)d_in[13];
    const float* decW1 = (const float*)d_in[14];
    const float* decb1 = (const float*)d_in[15];
    const float* ob    = (const float*)d_in[16];
    const float* acs   = (const float*)d_in[17];
    const float* times = (const float*)d_in[18];
    float* out = (float*)d_out;
    float* acl = (float*)d_ws;   // NB*NT*16 floats = 16.8 MB scratch

    acl_kernel<<<(NB * NT) / 256, 256, 0, stream>>>(acs, acW0, acb0, acW1, acb1, acl);
    ode_kernel<<<NB / 8, 256, 0, stream>>>(encW0, encb0, encW1, encb1,
                                           dynW0, dynb0, dynW1, dynb1,
                                           decW0, decb0, decW1, decb1,
                                           ob, times, acl, out);
}

// Round 3
// 816.985 us; speedup vs baseline: 1.3496x; 1.3496x over previous
//
#include <hip/hip_runtime.h>

#define NB 2048
#define NT 128

// ---------------------------------------------------------------------------
// Kernel 1: action-latent MLP  (B*T, 8) -> relu(64) -> (B*T, 16), into d_ws
// ---------------------------------------------------------------------------
__global__ __launch_bounds__(256, 4) void acl_kernel(
    const float* __restrict__ acs, const float* __restrict__ acW0,
    const float* __restrict__ acb0, const float* __restrict__ acW1,
    const float* __restrict__ acb1, float* __restrict__ aclout)
{
    __shared__ float sW0[64 * 8];
    __shared__ float sW1[16 * 64];
    __shared__ float sB0[64];
    __shared__ float sB1[16];
    const int tid = threadIdx.x;
    for (int i = tid; i < 64 * 8; i += 256) sW0[i] = acW0[i];
    for (int i = tid; i < 16 * 64; i += 256) sW1[i] = acW1[i];
    if (tid < 64) sB0[tid] = acb0[tid];
    if (tid < 16) sB1[tid] = acb1[tid];
    __syncthreads();

    const int row = blockIdx.x * 256 + tid;
    const float4 x0 = *(const float4*)&acs[row * 8];
    const float4 x1 = *(const float4*)&acs[row * 8 + 4];

    float o[16];
    #pragma unroll
    for (int m = 0; m < 16; ++m) o[m] = sB1[m];

    #pragma unroll
    for (int jc = 0; jc < 16; ++jc) {
        float hq[4];
        #pragma unroll
        for (int u = 0; u < 4; ++u) {
            const int j = jc * 4 + u;
            const float4 wa = *(const float4*)&sW0[j * 8];
            const float4 wb = *(const float4*)&sW0[j * 8 + 4];
            float hv = sB0[j];
            hv = fmaf(x0.x, wa.x, hv); hv = fmaf(x0.y, wa.y, hv);
            hv = fmaf(x0.z, wa.z, hv); hv = fmaf(x0.w, wa.w, hv);
            hv = fmaf(x1.x, wb.x, hv); hv = fmaf(x1.y, wb.y, hv);
            hv = fmaf(x1.z, wb.z, hv); hv = fmaf(x1.w, wb.w, hv);
            hq[u] = fmaxf(hv, 0.f);
        }
        #pragma unroll
        for (int m = 0; m < 16; ++m) {
            const float4 wv = *(const float4*)&sW1[m * 64 + jc * 4];
            o[m] = fmaf(hq[0], wv.x, o[m]);
            o[m] = fmaf(hq[1], wv.y, o[m]);
            o[m] = fmaf(hq[2], wv.z, o[m]);
            o[m] = fmaf(hq[3], wv.w, o[m]);
        }
    }
    float4* op = (float4*)&aclout[row * 16];
    op[0] = make_float4(o[0],  o[1],  o[2],  o[3]);
    op[1] = make_float4(o[4],  o[5],  o[6],  o[7]);
    op[2] = make_float4(o[8],  o[9],  o[10], o[11]);
    op[3] = make_float4(o[12], o[13], o[14], o[15]);
}

// ---------------------------------------------------------------------------
// Kernel 2 v5: encoder + Dopri5 time loop (v2 structure, decode EXTRACTED).
//  - identical feval / encoder / acl-part / time-stepping as the 845 µs v2
//    kernel -> bit-identical y trajectory.
//  - per save-step, stores y (32 floats) into out[row][0..31]; dec_kernel
//    decodes every row in place afterwards.
//  - dec weights no longer staged (LDS 54 KB -> ~29 KB), decode's ~105 VALU
//    instrs + 27 DS ops removed from the serial per-interval path.
// ---------------------------------------------------------------------------
__global__ __launch_bounds__(256, 2) void ode_kernel(
    const float* __restrict__ encW0, const float* __restrict__ encb0,
    const float* __restrict__ encW1, const float* __restrict__ encb1,
    const float* __restrict__ dynW0, const float* __restrict__ dynb0,
    const float* __restrict__ dynW1, const float* __restrict__ dynb1,
    const float* __restrict__ ob,    const float* __restrict__ times,
    const float* __restrict__ aclws, float* __restrict__ yio)
{
    __shared__ float sEncW0T[64 * 64];   // [k][j]
    __shared__ float sEncW1T[64 * 32];   // [j][m]
    __shared__ float sEncB0[64], sEncB1[32];
    __shared__ float xbuf[4][64];
    __shared__ float hbuf[4][64];
    __shared__ float tbuf[4][NT];

    const int tid = threadIdx.x;
    for (int i = tid; i < 64 * 64; i += 256) { int r = i >> 6, c = i & 63; sEncW0T[c * 64 + r] = encW0[i]; }
    for (int i = tid; i < 32 * 64; i += 256) { int r = i >> 6, c = i & 63; sEncW1T[c * 32 + r] = encW1[i]; }
    if (tid < 64) { sEncB0[tid] = encb0[tid]; }
    if (tid < 32) { sEncB1[tid] = encb1[tid]; }

    const int w    = tid >> 6;
    const int lane = tid & 63;
    const int bu   = __builtin_amdgcn_readfirstlane(blockIdx.x * 4 + w);
    const int m    = lane & 31;
    const int jh   = (lane >> 5) * 32;   // which half of j-space this lane reduces

    float* __restrict__ xb = xbuf[w];
    float* __restrict__ hb = hbuf[w];

    // dyn weights -> registers: lane j holds dynW0 row j (y-cols 0..31 then
    // acl-cols 32..47); lane holds half a dynW1 row (output m, j in [jh,jh+32)).
    float w0r[48];
    #pragma unroll
    for (int q = 0; q < 12; ++q) *(float4*)&w0r[q * 4] = *(const float4*)&dynW0[lane * 48 + q * 4];
    float w1r[32];
    #pragma unroll
    for (int q = 0; q < 8; ++q)  *(float4*)&w1r[q * 4] = *(const float4*)&dynW1[m * 64 + jh + q * 4];
    const float b0r = dynb0[lane];
    const float b1r = dynb1[m];

    tbuf[w][lane]      = times[bu * NT + lane];
    tbuf[w][64 + lane] = times[bu * NT + 64 + lane];

    __syncthreads();

    // f(x): xb[0..31] = y already written; hinit = b0 + acl-part of the dot
    auto feval = [&](float hinit) -> float {
        __builtin_amdgcn_wave_barrier();
        float4 xv[8];
        #pragma unroll
        for (int q = 0; q < 8; ++q) xv[q] = *(const float4*)&xb[q * 4];
        float a0 = hinit, a1 = 0.f, a2 = 0.f, a3 = 0.f;
        #pragma unroll
        for (int q = 0; q < 8; ++q) {
            a0 = fmaf(xv[q].x, w0r[q * 4 + 0], a0);
            a1 = fmaf(xv[q].y, w0r[q * 4 + 1], a1);
            a2 = fmaf(xv[q].z, w0r[q * 4 + 2], a2);
            a3 = fmaf(xv[q].w, w0r[q * 4 + 3], a3);
        }
        const float hj = fmaxf((a0 + a1) + (a2 + a3), 0.f);
        hb[lane] = hj;
        __builtin_amdgcn_wave_barrier();
        float4 hv[8];
        #pragma unroll
        for (int q = 0; q < 8; ++q) hv[q] = *(const float4*)&hb[jh + q * 4];
        float c0 = 0.f, c1 = 0.f, c2 = 0.f, c3 = 0.f;
        #pragma unroll
        for (int q = 0; q < 8; ++q) {
            c0 = fmaf(hv[q].x, w1r[q * 4 + 0], c0);
            c1 = fmaf(hv[q].y, w1r[q * 4 + 1], c1);
            c2 = fmaf(hv[q].z, w1r[q * 4 + 2], c2);
            c3 = fmaf(hv[q].w, w1r[q * 4 + 3], c3);
        }
        float part = (c0 + c1) + (c2 + c3);
        part += __shfl_xor(part, 32, 64);   // both halves now hold o_m
        return part + b1r;
    };

    // ---- encoder: ob(64) -> relu(64) -> y(32), y replicated in both halves
    float y;
    {
        xb[lane] = ob[bu * 64 + lane];
        __builtin_amdgcn_wave_barrier();
        float4 xv[16];
        #pragma unroll
        for (int q = 0; q < 16; ++q) xv[q] = *(const float4*)&xb[q * 4];
        float a0 = sEncB0[lane], a1 = 0.f, a2 = 0.f, a3 = 0.f;
        #pragma unroll
        for (int q = 0; q < 16; ++q) {
            a0 = fmaf(xv[q].x, sEncW0T[(q * 4 + 0) * 64 + lane], a0);
            a1 = fmaf(xv[q].y, sEncW0T[(q * 4 + 1) * 64 + lane], a1);
            a2 = fmaf(xv[q].z, sEncW0T[(q * 4 + 2) * 64 + lane], a2);
            a3 = fmaf(xv[q].w, sEncW0T[(q * 4 + 3) * 64 + lane], a3);
        }
        const float hj = fmaxf((a0 + a1) + (a2 + a3), 0.f);
        hb[lane] = hj;
        __builtin_amdgcn_wave_barrier();
        float4 hv[8];
        #pragma unroll
        for (int q = 0; q < 8; ++q) hv[q] = *(const float4*)&hb[jh + q * 4];
        float c0 = 0.f, c1 = 0.f, c2 = 0.f, c3 = 0.f;
        #pragma unroll
        for (int q = 0; q < 8; ++q) {
            c0 = fmaf(hv[q].x, sEncW1T[(jh + q * 4 + 0) * 32 + m], c0);
            c1 = fmaf(hv[q].y, sEncW1T[(jh + q * 4 + 1) * 32 + m], c1);
            c2 = fmaf(hv[q].z, sEncW1T[(jh + q * 4 + 2) * 32 + m], c2);
            c3 = fmaf(hv[q].w, sEncW1T[(jh + q * 4 + 3) * 32 + m], c3);
        }
        float part = (c0 + c1) + (c2 + c3);
        part += __shfl_xor(part, 32, 64);
        y = part + sEncB1[m];
    }

    // per-lane acl partial: aclPart = sum_k w0[lane][32+k] * acl[k]
    auto acl_part = [&](const float* __restrict__ ap) -> float {
        float4 a0 = *(const float4*)&ap[0];
        float4 a1 = *(const float4*)&ap[4];
        float4 a2 = *(const float4*)&ap[8];
        float4 a3 = *(const float4*)&ap[12];
        float s0 = 0.f, s1 = 0.f;
        s0 = fmaf(a0.x, w0r[32], s0); s1 = fmaf(a0.y, w0r[33], s1);
        s0 = fmaf(a0.z, w0r[34], s0); s1 = fmaf(a0.w, w0r[35], s1);
        s0 = fmaf(a1.x, w0r[36], s0); s1 = fmaf(a1.y, w0r[37], s1);
        s0 = fmaf(a1.z, w0r[38], s0); s1 = fmaf(a1.w, w0r[39], s1);
        s0 = fmaf(a2.x, w0r[40], s0); s1 = fmaf(a2.y, w0r[41], s1);
        s0 = fmaf(a2.z, w0r[42], s0); s1 = fmaf(a2.w, w0r[43], s1);
        s0 = fmaf(a3.x, w0r[44], s0); s1 = fmaf(a3.y, w0r[45], s1);
        s0 = fmaf(a3.z, w0r[46], s0); s1 = fmaf(a3.w, w0r[47], s1);
        return s0 + s1;
    };

    auto store_y = [&](float yv, int t) {
        if (lane < 32) yio[(size_t)(bu * NT + t) * 64 + lane] = yv;
    };

    float aclPartC = acl_part(aclws + (size_t)(bu * NT) * 16);
    store_y(y, 0);

    for (int i = 0; i < NT - 1; ++i) {
        const float t0v = tbuf[w][i];
        const float t1v = tbuf[w][i + 1];
        const float hh  = (t1v - t0v) * 0.5f;                       // /K, K=2
        const float aclPartN = acl_part(aclws + (size_t)(bu * NT + i + 1) * 16);

        #pragma unroll 1
        for (int sub = 0; sub < 2; ++sub) {
            const float tsub  = t0v + (float)sub * hh;
            // stage-6 time fl(tsub+hh): matches reference searchsorted('right')
            const bool  swap6 = (tsub + hh >= t1v);
            const float hpC = b0r + aclPartC;
            const float hp6 = b0r + (swap6 ? aclPartN : aclPartC);

            xb[m] = y;
            const float k1 = feval(hpC);
            xb[m] = fmaf(hh, 0.2f * k1, y);
            const float k2 = feval(hpC);
            xb[m] = fmaf(hh, 0.075f * k1 + 0.225f * k2, y);
            const float k3 = feval(hpC);
            xb[m] = fmaf(hh,
                (float)(44.0/45.0)*k1 + (float)(-56.0/15.0)*k2 + (float)(32.0/9.0)*k3, y);
            const float k4 = feval(hpC);
            xb[m] = fmaf(hh,
                (float)(19372.0/6561.0)*k1 + (float)(-25360.0/2187.0)*k2
              + (float)(64448.0/6561.0)*k3 + (float)(-212.0/729.0)*k4, y);
            const float k5 = feval(hpC);
            xb[m] = fmaf(hh,
                (float)(9017.0/3168.0)*k1 + (float)(-355.0/33.0)*k2
              + (float)(46732.0/5247.0)*k3 + (float)(49.0/176.0)*k4
              + (float)(-5103.0/18656.0)*k5, y);
            const float k6 = feval(hp6);
            y = fmaf(hh,
                (float)(35.0/384.0)*k1 + (float)(500.0/1113.0)*k3
              + (float)(125.0/192.0)*k4 + (float)(-2187.0/6784.0)*k5
              + (float)(11.0/84.0)*k6, y);
        }
        aclPartC = aclPartN;
        store_y(y, i + 1);
    }
}

// ---------------------------------------------------------------------------
// Kernel 3: decoder, one thread per (b,t) row, IN PLACE on out.
//  - reads y from out[row][0..31] (written by ode_kernel), writes the decoded
//    64 outputs to out[row][0..63]. Read-before-write within the thread.
//  - weights broadcast from LDS (uniform j per iteration -> conflict-free),
//    no cross-thread sync, no LDS round trips; 4096 waves (4/SIMD).
// ---------------------------------------------------------------------------
__global__ __launch_bounds__(256, 2) void dec_kernel(
    const float* __restrict__ decW0, const float* __restrict__ decb0,
    const float* __restrict__ decW1, const float* __restrict__ decb1,
    float* __restrict__ yio)
{
    __shared__ float sW0[64 * 32];   // [j][k] as stored
    __shared__ float sW1T[64 * 64];  // [j][n]
    __shared__ float sB0[64];
    __shared__ float sB1[64];
    const int tid = threadIdx.x;
    for (int i = tid; i < 64 * 32; i += 256) sW0[i] = decW0[i];
    for (int i = tid; i < 64 * 64; i += 256) { int n = i >> 6, j = i & 63; sW1T[j * 64 + n] = decW1[i]; }
    if (tid < 64) { sB0[tid] = decb0[tid]; sB1[tid] = decb1[tid]; }
    __syncthreads();

    const size_t row = (size_t)blockIdx.x * 256 + tid;
    float* rp = &yio[row * 64];

    float4 xr[8];
    #pragma unroll
    for (int q = 0; q < 8; ++q) xr[q] = *(const float4*)&rp[q * 4];

    float o[64];
    #pragma unroll
    for (int n = 0; n < 64; ++n) o[n] = sB1[n];

    #pragma unroll 4
    for (int j = 0; j < 64; ++j) {
        float a0 = sB0[j], a1 = 0.f, a2 = 0.f, a3 = 0.f;
        #pragma unroll
        for (int q = 0; q < 8; ++q) {
            const float4 wv = *(const float4*)&sW0[j * 32 + q * 4];
            a0 = fmaf(xr[q].x, wv.x, a0);
            a1 = fmaf(xr[q].y, wv.y, a1);
            a2 = fmaf(xr[q].z, wv.z, a2);
            a3 = fmaf(xr[q].w, wv.w, a3);
        }
        const float hj = fmaxf((a0 + a1) + (a2 + a3), 0.f);
        #pragma unroll
        for (int q = 0; q < 16; ++q) {
            const float4 wv = *(const float4*)&sW1T[j * 64 + q * 4];
            o[q * 4 + 0] = fmaf(hj, wv.x, o[q * 4 + 0]);
            o[q * 4 + 1] = fmaf(hj, wv.y, o[q * 4 + 1]);
            o[q * 4 + 2] = fmaf(hj, wv.z, o[q * 4 + 2]);
            o[q * 4 + 3] = fmaf(hj, wv.w, o[q * 4 + 3]);
        }
    }

    #pragma unroll
    for (int q = 0; q < 16; ++q)
        *(float4*)&rp[q * 4] = make_float4(o[q * 4], o[q * 4 + 1], o[q * 4 + 2], o[q * 4 + 3]);
}

extern "C" void kernel_launch(void* const* d_in, const int* in_sizes, int n_in,
                              void* d_out, int out_size, void* d_ws, size_t ws_size,
                              hipStream_t stream)
{
    const float* encW0 = (const float*)d_in[0];
    const float* encb0 = (const float*)d_in[1];
    const float* encW1 = (const float*)d_in[2];
    const float* encb1 = (const float*)d_in[3];
    const float* acW0  = (const float*)d_in[4];
    const float* acb0  = (const float*)d_in[5];
    const float* acW1  = (const float*)d_in[6];
    const float* acb1  = (const float*)d_in[7];
    const float* dynW0 = (const float*)d_in[8];
    const float* dynb0 = (const float*)d_in[9];
    const float* dynW1 = (const float*)d_in[10];
    const float* dynb1 = (const float*)d_in[11];
    const float* decW0 = (const float*)d_in[12];
    const float* decb0 = (const float*)d_in[13];
    const float* decW1 = (const float*)d_in[14];
    const float* decb1 = (const float*)d_in[15];
    const float* ob    = (const float*)d_in[16];
    const float* acs   = (const float*)d_in[17];
    const float* times = (const float*)d_in[18];
    float* out = (float*)d_out;
    float* acl = (float*)d_ws;   // NB*NT*16 floats = 16.8 MB scratch

    acl_kernel<<<(NB * NT) / 256, 256, 0, stream>>>(acs, acW0, acb0, acW1, acb1, acl);
    ode_kernel<<<NB / 4, 256, 0, stream>>>(encW0, encb0, encW1, encb1,
                                           dynW0, dynb0, dynW1, dynb1,
                                           ob, times, acl, out);
    dec_kernel<<<(NB * NT) / 256, 256, 0, stream>>>(decW0, decb0, decW1, decb1, out);
}

// Round 5
// 705.351 us; speedup vs baseline: 1.5632x; 1.1583x over previous
//
#include <hip/hip_runtime.h>

#define NB 2048
#define NT 128

typedef float v2f __attribute__((ext_vector_type(2)));

static __device__ __forceinline__ v2f pkfma(v2f a, v2f b, v2f c) {
#if __has_builtin(__builtin_elementwise_fma)
    return __builtin_elementwise_fma(a, b, c);
#else
    v2f r; r.x = fmaf(a.x, b.x, c.x); r.y = fmaf(a.y, b.y, c.y); return r;
#endif
}
static __device__ __forceinline__ v2f mkv2(float x, float y) { v2f r; r.x = x; r.y = y; return r; }

// ---------------------------------------------------------------------------
// Kernel 1: action-latent MLP  (B*T, 8) -> relu(64) -> (B*T, 16), into d_ws
// ---------------------------------------------------------------------------
__global__ __launch_bounds__(256, 4) void acl_kernel(
    const float* __restrict__ acs, const float* __restrict__ acW0,
    const float* __restrict__ acb0, const float* __restrict__ acW1,
    const float* __restrict__ acb1, float* __restrict__ aclout)
{
    __shared__ float sW0[64 * 8];
    __shared__ float sW1[16 * 64];
    __shared__ float sB0[64];
    __shared__ float sB1[16];
    const int tid = threadIdx.x;
    for (int i = tid; i < 64 * 8; i += 256) sW0[i] = acW0[i];
    for (int i = tid; i < 16 * 64; i += 256) sW1[i] = acW1[i];
    if (tid < 64) sB0[tid] = acb0[tid];
    if (tid < 16) sB1[tid] = acb1[tid];
    __syncthreads();

    const int row = blockIdx.x * 256 + tid;
    const float4 x0 = *(const float4*)&acs[row * 8];
    const float4 x1 = *(const float4*)&acs[row * 8 + 4];

    float o[16];
    #pragma unroll
    for (int m = 0; m < 16; ++m) o[m] = sB1[m];

    #pragma unroll
    for (int jc = 0; jc < 16; ++jc) {
        float hq[4];
        #pragma unroll
        for (int u = 0; u < 4; ++u) {
            const int j = jc * 4 + u;
            const float4 wa = *(const float4*)&sW0[j * 8];
            const float4 wb = *(const float4*)&sW0[j * 8 + 4];
            float hv = sB0[j];
            hv = fmaf(x0.x, wa.x, hv); hv = fmaf(x0.y, wa.y, hv);
            hv = fmaf(x0.z, wa.z, hv); hv = fmaf(x0.w, wa.w, hv);
            hv = fmaf(x1.x, wb.x, hv); hv = fmaf(x1.y, wb.y, hv);
            hv = fmaf(x1.z, wb.z, hv); hv = fmaf(x1.w, wb.w, hv);
            hq[u] = fmaxf(hv, 0.f);
        }
        #pragma unroll
        for (int m = 0; m < 16; ++m) {
            const float4 wv = *(const float4*)&sW1[m * 64 + jc * 4];
            o[m] = fmaf(hq[0], wv.x, o[m]);
            o[m] = fmaf(hq[1], wv.y, o[m]);
            o[m] = fmaf(hq[2], wv.z, o[m]);
            o[m] = fmaf(hq[3], wv.w, o[m]);
        }
    }
    float4* op = (float4*)&aclout[row * 16];
    op[0] = make_float4(o[0],  o[1],  o[2],  o[3]);
    op[1] = make_float4(o[4],  o[5],  o[6],  o[7]);
    op[2] = make_float4(o[8],  o[9],  o[10], o[11]);
    op[3] = make_float4(o[12], o[13], o[14], o[15]);
}

// ---------------------------------------------------------------------------
// Kernel 2 v6: v5 structure with all hot dot products converted to packed
// fp32 (v_pk_fma_f32, 2 FMA/instr). DS traffic, fences, time-stepping, and
// the y-trajectory math semantics (fused FMA) unchanged.
// ---------------------------------------------------------------------------
__global__ __launch_bounds__(256, 2) void ode_kernel(
    const float* __restrict__ encW0, const float* __restrict__ encb0,
    const float* __restrict__ encW1, const float* __restrict__ encb1,
    const float* __restrict__ dynW0, const float* __restrict__ dynb0,
    const float* __restrict__ dynW1, const float* __restrict__ dynb1,
    const float* __restrict__ ob,    const float* __restrict__ times,
    const float* __restrict__ aclws, float* __restrict__ yio)
{
    __shared__ float sEncW0T[64 * 64];   // [k][j]
    __shared__ float sEncW1T[64 * 32];   // [j][m]
    __shared__ float sEncB0[64], sEncB1[32];
    __shared__ float xbuf[4][64];
    __shared__ float hbuf[4][64];
    __shared__ float tbuf[4][NT];

    const int tid = threadIdx.x;
    for (int i = tid; i < 64 * 64; i += 256) { int r = i >> 6, c = i & 63; sEncW0T[c * 64 + r] = encW0[i]; }
    for (int i = tid; i < 32 * 64; i += 256) { int r = i >> 6, c = i & 63; sEncW1T[c * 32 + r] = encW1[i]; }
    if (tid < 64) { sEncB0[tid] = encb0[tid]; }
    if (tid < 32) { sEncB1[tid] = encb1[tid]; }

    const int w    = tid >> 6;
    const int lane = tid & 63;
    const int bu   = __builtin_amdgcn_readfirstlane(blockIdx.x * 4 + w);
    const int m    = lane & 31;
    const int jh   = (lane >> 5) * 32;   // which half of j-space this lane reduces

    float* __restrict__ xb = xbuf[w];
    float* __restrict__ hb = hbuf[w];

    // dyn weights -> registers: lane j holds dynW0 row j (y-cols 0..31 then
    // acl-cols 32..47); lane holds half a dynW1 row (output m, j in [jh,jh+32)).
    float w0r[48];
    #pragma unroll
    for (int q = 0; q < 12; ++q) *(float4*)&w0r[q * 4] = *(const float4*)&dynW0[lane * 48 + q * 4];
    float w1r[32];
    #pragma unroll
    for (int q = 0; q < 8; ++q)  *(float4*)&w1r[q * 4] = *(const float4*)&dynW1[m * 64 + jh + q * 4];
    const float b0r = dynb0[lane];
    const float b1r = dynb1[m];

    tbuf[w][lane]      = times[bu * NT + lane];
    tbuf[w][64 + lane] = times[bu * NT + 64 + lane];

    __syncthreads();

    // f(x): xb[0..31] = y already written; hinit = b0 + acl-part of the dot
    auto feval = [&](float hinit) -> float {
        __builtin_amdgcn_wave_barrier();
        float xr[32];
        #pragma unroll
        for (int q = 0; q < 8; ++q) *(float4*)&xr[q * 4] = *(const float4*)&xb[q * 4];
        const v2f* xp  = (const v2f*)xr;
        const v2f* wp  = (const v2f*)w0r;
        v2f a0 = mkv2(hinit, 0.f), a1 = mkv2(0.f, 0.f);
        #pragma unroll
        for (int q = 0; q < 16; q += 2) {
            a0 = pkfma(xp[q],     wp[q],     a0);
            a1 = pkfma(xp[q + 1], wp[q + 1], a1);
        }
        const float hj = fmaxf((a0.x + a1.x) + (a0.y + a1.y), 0.f);
        hb[lane] = hj;
        __builtin_amdgcn_wave_barrier();
        float hr[32];
        #pragma unroll
        for (int q = 0; q < 8; ++q) *(float4*)&hr[q * 4] = *(const float4*)&hb[jh + q * 4];
        const v2f* hp  = (const v2f*)hr;
        const v2f* w1p = (const v2f*)w1r;
        v2f c0 = mkv2(0.f, 0.f), c1 = mkv2(0.f, 0.f);
        #pragma unroll
        for (int q = 0; q < 16; q += 2) {
            c0 = pkfma(hp[q],     w1p[q],     c0);
            c1 = pkfma(hp[q + 1], w1p[q + 1], c1);
        }
        float part = (c0.x + c1.x) + (c0.y + c1.y);
        part += __shfl_xor(part, 32, 64);   // both halves now hold o_m
        return part + b1r;
    };

    // ---- encoder: ob(64) -> relu(64) -> y(32), y replicated in both halves
    float y;
    {
        xb[lane] = ob[bu * 64 + lane];
        __builtin_amdgcn_wave_barrier();
        float4 xv[16];
        #pragma unroll
        for (int q = 0; q < 16; ++q) xv[q] = *(const float4*)&xb[q * 4];
        float a0 = sEncB0[lane], a1 = 0.f, a2 = 0.f, a3 = 0.f;
        #pragma unroll
        for (int q = 0; q < 16; ++q) {
            a0 = fmaf(xv[q].x, sEncW0T[(q * 4 + 0) * 64 + lane], a0);
            a1 = fmaf(xv[q].y, sEncW0T[(q * 4 + 1) * 64 + lane], a1);
            a2 = fmaf(xv[q].z, sEncW0T[(q * 4 + 2) * 64 + lane], a2);
            a3 = fmaf(xv[q].w, sEncW0T[(q * 4 + 3) * 64 + lane], a3);
        }
        const float hj = fmaxf((a0 + a1) + (a2 + a3), 0.f);
        hb[lane] = hj;
        __builtin_amdgcn_wave_barrier();
        float4 hv[8];
        #pragma unroll
        for (int q = 0; q < 8; ++q) hv[q] = *(const float4*)&hb[jh + q * 4];
        float c0 = 0.f, c1 = 0.f, c2 = 0.f, c3 = 0.f;
        #pragma unroll
        for (int q = 0; q < 8; ++q) {
            c0 = fmaf(hv[q].x, sEncW1T[(jh + q * 4 + 0) * 32 + m], c0);
            c1 = fmaf(hv[q].y, sEncW1T[(jh + q * 4 + 1) * 32 + m], c1);
            c2 = fmaf(hv[q].z, sEncW1T[(jh + q * 4 + 2) * 32 + m], c2);
            c3 = fmaf(hv[q].w, sEncW1T[(jh + q * 4 + 3) * 32 + m], c3);
        }
        float part = (c0 + c1) + (c2 + c3);
        part += __shfl_xor(part, 32, 64);
        y = part + sEncB1[m];
    }

    // per-lane acl partial: aclPart = sum_k w0[lane][32+k] * acl[k]
    auto acl_part = [&](const float* __restrict__ ap) -> float {
        float ar[16];
        #pragma unroll
        for (int q = 0; q < 4; ++q) *(float4*)&ar[q * 4] = *(const float4*)&ap[q * 4];
        const v2f* a2 = (const v2f*)ar;
        const v2f* wq = (const v2f*)&w0r[32];
        v2f s0 = mkv2(0.f, 0.f), s1 = mkv2(0.f, 0.f);
        #pragma unroll
        for (int q = 0; q < 8; q += 2) {
            s0 = pkfma(a2[q],     wq[q],     s0);
            s1 = pkfma(a2[q + 1], wq[q + 1], s1);
        }
        const v2f s = s0 + s1;
        return s.x + s.y;
    };

    auto store_y = [&](float yv, int t) {
        if (lane < 32) yio[(size_t)(bu * NT + t) * 64 + lane] = yv;
    };

    float aclPartC = acl_part(aclws + (size_t)(bu * NT) * 16);
    store_y(y, 0);

    for (int i = 0; i < NT - 1; ++i) {
        const float t0v = tbuf[w][i];
        const float t1v = tbuf[w][i + 1];
        const float hh  = (t1v - t0v) * 0.5f;                       // /K, K=2
        const float aclPartN = acl_part(aclws + (size_t)(bu * NT + i + 1) * 16);

        #pragma unroll 1
        for (int sub = 0; sub < 2; ++sub) {
            const float tsub  = t0v + (float)sub * hh;
            // stage-6 time fl(tsub+hh): matches reference searchsorted('right')
            const bool  swap6 = (tsub + hh >= t1v);
            const float hpC = b0r + aclPartC;
            const float hp6 = b0r + (swap6 ? aclPartN : aclPartC);

            xb[m] = y;
            const float k1 = feval(hpC);
            xb[m] = fmaf(hh, 0.2f * k1, y);
            const float k2 = feval(hpC);
            xb[m] = fmaf(hh, 0.075f * k1 + 0.225f * k2, y);
            const float k3 = feval(hpC);
            xb[m] = fmaf(hh,
                (float)(44.0/45.0)*k1 + (float)(-56.0/15.0)*k2 + (float)(32.0/9.0)*k3, y);
            const float k4 = feval(hpC);
            xb[m] = fmaf(hh,
                (float)(19372.0/6561.0)*k1 + (float)(-25360.0/2187.0)*k2
              + (float)(64448.0/6561.0)*k3 + (float)(-212.0/729.0)*k4, y);
            const float k5 = feval(hpC);
            xb[m] = fmaf(hh,
                (float)(9017.0/3168.0)*k1 + (float)(-355.0/33.0)*k2
              + (float)(46732.0/5247.0)*k3 + (float)(49.0/176.0)*k4
              + (float)(-5103.0/18656.0)*k5, y);
            const float k6 = feval(hp6);
            y = fmaf(hh,
                (float)(35.0/384.0)*k1 + (float)(500.0/1113.0)*k3
              + (float)(125.0/192.0)*k4 + (float)(-2187.0/6784.0)*k5
              + (float)(11.0/84.0)*k6, y);
        }
        aclPartC = aclPartN;
        store_y(y, i + 1);
    }
}

// ---------------------------------------------------------------------------
// Kernel 3: decoder, one thread per (b,t) row, IN PLACE on out. Packed fp32.
// ---------------------------------------------------------------------------
__global__ __launch_bounds__(256, 2) void dec_kernel(
    const float* __restrict__ decW0, const float* __restrict__ decb0,
    const float* __restrict__ decW1, const float* __restrict__ decb1,
    float* __restrict__ yio)
{
    __shared__ float sW0[64 * 32];   // [j][k] as stored
    __shared__ float sW1T[64 * 64];  // [j][n]
    __shared__ float sB0[64];
    __shared__ float sB1[64];
    const int tid = threadIdx.x;
    for (int i = tid; i < 64 * 32; i += 256) sW0[i] = decW0[i];
    for (int i = tid; i < 64 * 64; i += 256) { int n = i >> 6, j = i & 63; sW1T[j * 64 + n] = decW1[i]; }
    if (tid < 64) { sB0[tid] = decb0[tid]; sB1[tid] = decb1[tid]; }
    __syncthreads();

    const size_t row = (size_t)blockIdx.x * 256 + tid;
    float* rp = &yio[row * 64];

    float xr[32];
    #pragma unroll
    for (int q = 0; q < 8; ++q) *(float4*)&xr[q * 4] = *(const float4*)&rp[q * 4];

    v2f o2[32];
    #pragma unroll
    for (int n = 0; n < 32; ++n) o2[n] = mkv2(sB1[2 * n], sB1[2 * n + 1]);

    #pragma unroll 4
    for (int j = 0; j < 64; ++j) {
        v2f a0 = mkv2(sB0[j], 0.f), a1 = mkv2(0.f, 0.f);
        #pragma unroll
        for (int q = 0; q < 8; ++q) {
            const float4 wv = *(const float4*)&sW0[j * 32 + q * 4];
            a0 = pkfma(*(const v2f*)&xr[q * 4],     mkv2(wv.x, wv.y), a0);
            a1 = pkfma(*(const v2f*)&xr[q * 4 + 2], mkv2(wv.z, wv.w), a1);
        }
        const float hj = fmaxf((a0.x + a1.x) + (a0.y + a1.y), 0.f);
        const v2f h2 = mkv2(hj, hj);
        #pragma unroll
        for (int q = 0; q < 16; ++q) {
            const float4 wv = *(const float4*)&sW1T[j * 64 + q * 4];
            o2[2 * q]     = pkfma(h2, mkv2(wv.x, wv.y), o2[2 * q]);
            o2[2 * q + 1] = pkfma(h2, mkv2(wv.z, wv.w), o2[2 * q + 1]);
        }
    }

    #pragma unroll
    for (int q = 0; q < 16; ++q)
        *(float4*)&rp[q * 4] = make_float4(o2[2 * q].x, o2[2 * q].y,
                                           o2[2 * q + 1].x, o2[2 * q + 1].y);
}

extern "C" void kernel_launch(void* const* d_in, const int* in_sizes, int n_in,
                              void* d_out, int out_size, void* d_ws, size_t ws_size,
                              hipStream_t stream)
{
    const float* encW0 = (const float*)d_in[0];
    const float* encb0 = (const float*)d_in[1];
    const float* encW1 = (const float*)d_in[2];
    const float* encb1 = (const float*)d_in[3];
    const float* acW0  = (const float*)d_in[4];
    const float* acb0  = (const float*)d_in[5];
    const float* acW1  = (const float*)d_in[6];
    const float* acb1  = (const float*)d_in[7];
    const float* dynW0 = (const float*)d_in[8];
    const float* dynb0 = (const float*)d_in[9];
    const float* dynW1 = (const float*)d_in[10];
    const float* dynb1 = (const float*)d_in[11];
    const float* decW0 = (const float*)d_in[12];
    const float* decb0 = (const float*)d_in[13];
    const float* decW1 = (const float*)d_in[14];
    const float* decb1 = (const float*)d_in[15];
    const float* ob    = (const float*)d_in[16];
    const float* acs   = (const float*)d_in[17];
    const float* times = (const float*)d_in[18];
    float* out = (float*)d_out;
    float* acl = (float*)d_ws;   // NB*NT*16 floats = 16.8 MB scratch

    acl_kernel<<<(NB * NT) / 256, 256, 0, stream>>>(acs, acW0, acb0, acW1, acb1, acl);
    ode_kernel<<<NB / 4, 256, 0, stream>>>(encW0, encb0, encW1, encb1,
                                           dynW0, dynb0, dynW1, dynb1,
                                           ob, times, acl, out);
    dec_kernel<<<(NB * NT) / 256, 256, 0, stream>>>(decW0, decb0, decW1, decb1, out);
}

// Round 6
// 614.099 us; speedup vs baseline: 1.7955x; 1.1486x over previous
//
#include <hip/hip_runtime.h>

#define NB 2048
#define NT 128

typedef float v2f __attribute__((ext_vector_type(2)));

static __device__ __forceinline__ v2f pkfma(v2f a, v2f b, v2f c) {
#if __has_builtin(__builtin_elementwise_fma)
    return __builtin_elementwise_fma(a, b, c);
#else
    v2f r; r.x = fmaf(a.x, b.x, c.x); r.y = fmaf(a.y, b.y, c.y); return r;
#endif
}
static __device__ __forceinline__ v2f mkv2(float x, float y) { v2f r; r.x = x; r.y = y; return r; }

// ---------------------------------------------------------------------------
// Kernel 1: action-latent MLP  (B*T, 8) -> relu(64) -> (B*T, 16), into d_ws
// ---------------------------------------------------------------------------
__global__ __launch_bounds__(256, 4) void acl_kernel(
    const float* __restrict__ acs, const float* __restrict__ acW0,
    const float* __restrict__ acb0, const float* __restrict__ acW1,
    const float* __restrict__ acb1, float* __restrict__ aclout)
{
    __shared__ float sW0[64 * 8];
    __shared__ float sW1[16 * 64];
    __shared__ float sB0[64];
    __shared__ float sB1[16];
    const int tid = threadIdx.x;
    for (int i = tid; i < 64 * 8; i += 256) sW0[i] = acW0[i];
    for (int i = tid; i < 16 * 64; i += 256) sW1[i] = acW1[i];
    if (tid < 64) sB0[tid] = acb0[tid];
    if (tid < 16) sB1[tid] = acb1[tid];
    __syncthreads();

    const int row = blockIdx.x * 256 + tid;
    const float4 x0 = *(const float4*)&acs[row * 8];
    const float4 x1 = *(const float4*)&acs[row * 8 + 4];

    float o[16];
    #pragma unroll
    for (int m = 0; m < 16; ++m) o[m] = sB1[m];

    #pragma unroll
    for (int jc = 0; jc < 16; ++jc) {
        float hq[4];
        #pragma unroll
        for (int u = 0; u < 4; ++u) {
            const int j = jc * 4 + u;
            const float4 wa = *(const float4*)&sW0[j * 8];
            const float4 wb = *(const float4*)&sW0[j * 8 + 4];
            float hv = sB0[j];
            hv = fmaf(x0.x, wa.x, hv); hv = fmaf(x0.y, wa.y, hv);
            hv = fmaf(x0.z, wa.z, hv); hv = fmaf(x0.w, wa.w, hv);
            hv = fmaf(x1.x, wb.x, hv); hv = fmaf(x1.y, wb.y, hv);
            hv = fmaf(x1.z, wb.z, hv); hv = fmaf(x1.w, wb.w, hv);
            hq[u] = fmaxf(hv, 0.f);
        }
        #pragma unroll
        for (int m = 0; m < 16; ++m) {
            const float4 wv = *(const float4*)&sW1[m * 64 + jc * 4];
            o[m] = fmaf(hq[0], wv.x, o[m]);
            o[m] = fmaf(hq[1], wv.y, o[m]);
            o[m] = fmaf(hq[2], wv.z, o[m]);
            o[m] = fmaf(hq[3], wv.w, o[m]);
        }
    }
    float4* op = (float4*)&aclout[row * 16];
    op[0] = make_float4(o[0],  o[1],  o[2],  o[3]);
    op[1] = make_float4(o[4],  o[5],  o[6],  o[7]);
    op[2] = make_float4(o[8],  o[9],  o[10], o[11]);
    op[3] = make_float4(o[12], o[13], o[14], o[15]);
}

// ---------------------------------------------------------------------------
// Kernel 2 v7: stage recurrence in the PRE-ACTIVATION domain.
//   a_s = a_1 + hh*sum_r A_sr * g_r,  g_r = M*h_r + v,  M = W0y*W1, v = W0y*b1
//   a_1 = W0y*y + b0 + aclPart   (recomputed from y each sub-step)
//   y  += hh*(W1*hacc + b1),  hacc = sum_s B_s*h_s
//  -> per sub-step: 1 x-broadcast + 5 h-broadcasts + 1 hacc-broadcast
//     (7 LDS round trips, ~71 DS instrs vs 12 / ~114 in v6).
//  g-dot split across lane pairs (lane j: own half of rows j and j^32,
//  combined by one shfl_xor) so h reads stay 8xb128 per stage.
// ---------------------------------------------------------------------------
__global__ __launch_bounds__(256, 2) void ode_kernel(
    const float* __restrict__ encW0, const float* __restrict__ encb0,
    const float* __restrict__ encW1, const float* __restrict__ encb1,
    const float* __restrict__ dynW0, const float* __restrict__ dynb0,
    const float* __restrict__ dynW1, const float* __restrict__ dynb1,
    const float* __restrict__ ob,    const float* __restrict__ times,
    const float* __restrict__ aclws, float* __restrict__ yio)
{
    __shared__ float sEncW0T[64 * 64];   // [k][j]
    __shared__ float sEncW1T[64 * 32];   // [j][m]
    __shared__ float sW0s[64 * 32];      // W0y rows: [j][m]
    __shared__ float sW1T[64 * 32];      // W1 cols:  [j'][m]
    __shared__ float sM[64 * 64];        // M[j][j'] = sum_m W0y[j][m] W1[m][j']
    __shared__ float sEncB0[64], sEncB1[32], sB1d[32];
    __shared__ float xbuf[4][64];
    __shared__ float hbuf[4][64];
    __shared__ float tbuf[4][NT];

    const int tid = threadIdx.x;
    for (int i = tid; i < 64 * 64; i += 256) { int r = i >> 6, c = i & 63; sEncW0T[c * 64 + r] = encW0[i]; }
    for (int i = tid; i < 32 * 64; i += 256) { int r = i >> 6, c = i & 63; sEncW1T[c * 32 + r] = encW1[i]; }
    for (int i = tid; i < 64 * 32; i += 256) { int j = i >> 5, mm = i & 31; sW0s[i] = dynW0[j * 48 + mm]; }
    for (int i = tid; i < 64 * 32; i += 256) { int c = i >> 5, mm = i & 31; sW1T[i] = dynW1[mm * 64 + c]; }
    if (tid < 64) { sEncB0[tid] = encb0[tid]; }
    if (tid < 32) { sEncB1[tid] = encb1[tid]; sB1d[tid] = dynb1[tid]; }
    __syncthreads();

    // ---- compute sM cooperatively: thread t -> row j = t>>2, 16 cols
    {
        const int j  = tid >> 2;
        const int cg = (tid & 3) * 16;
        float4 wr[8];
        #pragma unroll
        for (int q = 0; q < 8; ++q) wr[q] = *(const float4*)&sW0s[j * 32 + q * 4];
        #pragma unroll 2
        for (int k = 0; k < 16; ++k) {
            const int c = cg + k;
            v2f s0 = mkv2(0.f, 0.f), s1 = mkv2(0.f, 0.f);
            #pragma unroll
            for (int q = 0; q < 8; ++q) {
                const float4 t4 = *(const float4*)&sW1T[c * 32 + q * 4];
                s0 = pkfma(mkv2(t4.x, t4.y), mkv2(wr[q].x, wr[q].y), s0);
                s1 = pkfma(mkv2(t4.z, t4.w), mkv2(wr[q].z, wr[q].w), s1);
            }
            sM[j * 64 + c] = (s0.x + s1.x) + (s0.y + s1.y);
        }
    }
    __syncthreads();

    const int w    = tid >> 6;
    const int lane = tid & 63;
    const int bu   = __builtin_amdgcn_readfirstlane(blockIdx.x * 4 + w);
    const int m    = lane & 31;
    const int H    = lane & 32;          // which half of j'-space this lane reads

    float* __restrict__ xb = xbuf[w];
    float* __restrict__ hb = hbuf[w];

    // per-lane weights: W0 row (y-cols + acl-cols), W1 half-row, M half-rows
    float w0r[48];
    #pragma unroll
    for (int q = 0; q < 12; ++q) *(float4*)&w0r[q * 4] = *(const float4*)&dynW0[lane * 48 + q * 4];
    float w1r[32];
    #pragma unroll
    for (int q = 0; q < 8; ++q)  *(float4*)&w1r[q * 4] = *(const float4*)&dynW1[m * 64 + H + q * 4];
    float Ma[32], Mb[32];
    #pragma unroll
    for (int q = 0; q < 8; ++q) *(float4*)&Ma[q * 4] = *(const float4*)&sM[lane * 64 + H + q * 4];
    #pragma unroll
    for (int q = 0; q < 8; ++q) *(float4*)&Mb[q * 4] = *(const float4*)&sM[(lane ^ 32) * 64 + H + q * 4];
    const float b0r = dynb0[lane];
    const float b1r = dynb1[m];

    // vj = W0y[lane,:] . b1
    float vj;
    {
        v2f s0 = mkv2(0.f, 0.f), s1 = mkv2(0.f, 0.f);
        const v2f* wp = (const v2f*)w0r;
        const v2f* bp = (const v2f*)sB1d;
        #pragma unroll
        for (int q = 0; q < 16; q += 2) {
            s0 = pkfma(bp[q],     wp[q],     s0);
            s1 = pkfma(bp[q + 1], wp[q + 1], s1);
        }
        vj = (s0.x + s1.x) + (s0.y + s1.y);
    }

    tbuf[w][lane]      = times[bu * NT + lane];
    tbuf[w][64 + lane] = times[bu * NT + 64 + lane];
    __builtin_amdgcn_wave_barrier();

    // g projection: broadcast h (this lane's h_j), return hh-unscaled M*h + v
    auto gproj = [&](float hsv) -> float {
        __builtin_amdgcn_wave_barrier();
        hb[lane] = hsv;
        __builtin_amdgcn_wave_barrier();
        float hr[32];
        #pragma unroll
        for (int q = 0; q < 8; ++q) *(float4*)&hr[q * 4] = *(const float4*)&hb[H + q * 4];
        const v2f* hp = (const v2f*)hr;
        const v2f* ma = (const v2f*)Ma;
        const v2f* mb = (const v2f*)Mb;
        v2f o0 = mkv2(0.f, 0.f), o1 = mkv2(0.f, 0.f);
        v2f p0 = mkv2(0.f, 0.f), p1 = mkv2(0.f, 0.f);
        #pragma unroll
        for (int q = 0; q < 16; q += 2) {
            o0 = pkfma(hp[q],     ma[q],     o0);
            o1 = pkfma(hp[q + 1], ma[q + 1], o1);
            p0 = pkfma(hp[q],     mb[q],     p0);
            p1 = pkfma(hp[q + 1], mb[q + 1], p1);
        }
        const float own = (o0.x + o1.x) + (o0.y + o1.y);
        float par = (p0.x + p1.x) + (p0.y + p1.y);
        par = __shfl_xor(par, 32, 64);
        return own + par + vj;
    };

    // ---- encoder: ob(64) -> relu(64) -> y(32), y replicated in both halves
    float y;
    {
        xb[lane] = ob[bu * 64 + lane];
        __builtin_amdgcn_wave_barrier();
        float4 xv[16];
        #pragma unroll
        for (int q = 0; q < 16; ++q) xv[q] = *(const float4*)&xb[q * 4];
        float a0 = sEncB0[lane], a1 = 0.f, a2 = 0.f, a3 = 0.f;
        #pragma unroll
        for (int q = 0; q < 16; ++q) {
            a0 = fmaf(xv[q].x, sEncW0T[(q * 4 + 0) * 64 + lane], a0);
            a1 = fmaf(xv[q].y, sEncW0T[(q * 4 + 1) * 64 + lane], a1);
            a2 = fmaf(xv[q].z, sEncW0T[(q * 4 + 2) * 64 + lane], a2);
            a3 = fmaf(xv[q].w, sEncW0T[(q * 4 + 3) * 64 + lane], a3);
        }
        const float hj = fmaxf((a0 + a1) + (a2 + a3), 0.f);
        hb[lane] = hj;
        __builtin_amdgcn_wave_barrier();
        float4 hv[8];
        #pragma unroll
        for (int q = 0; q < 8; ++q) hv[q] = *(const float4*)&hb[H + q * 4];
        float c0 = 0.f, c1 = 0.f, c2 = 0.f, c3 = 0.f;
        #pragma unroll
        for (int q = 0; q < 8; ++q) {
            c0 = fmaf(hv[q].x, sEncW1T[(H + q * 4 + 0) * 32 + m], c0);
            c1 = fmaf(hv[q].y, sEncW1T[(H + q * 4 + 1) * 32 + m], c1);
            c2 = fmaf(hv[q].z, sEncW1T[(H + q * 4 + 2) * 32 + m], c2);
            c3 = fmaf(hv[q].w, sEncW1T[(H + q * 4 + 3) * 32 + m], c3);
        }
        float part = (c0 + c1) + (c2 + c3);
        part += __shfl_xor(part, 32, 64);
        y = part + sEncB1[m];
    }

    // per-lane acl partial: aclPart = sum_k w0[lane][32+k] * acl[k]
    auto acl_part = [&](const float* __restrict__ ap) -> float {
        float ar[16];
        #pragma unroll
        for (int q = 0; q < 4; ++q) *(float4*)&ar[q * 4] = *(const float4*)&ap[q * 4];
        const v2f* a2 = (const v2f*)ar;
        const v2f* wq = (const v2f*)&w0r[32];
        v2f s0 = mkv2(0.f, 0.f), s1 = mkv2(0.f, 0.f);
        #pragma unroll
        for (int q = 0; q < 8; q += 2) {
            s0 = pkfma(a2[q],     wq[q],     s0);
            s1 = pkfma(a2[q + 1], wq[q + 1], s1);
        }
        const v2f s = s0 + s1;
        return s.x + s.y;
    };

    auto store_y = [&](float yv, int t) {
        if (lane < 32) yio[(size_t)(bu * NT + t) * 64 + lane] = yv;
    };

    float aclPartC = acl_part(aclws + (size_t)(bu * NT) * 16);
    store_y(y, 0);

    for (int i = 0; i < NT - 1; ++i) {
        const float t0v = tbuf[w][i];
        const float t1v = tbuf[w][i + 1];
        const float hh  = (t1v - t0v) * 0.5f;                       // /K, K=2
        const float aclPartN = acl_part(aclws + (size_t)(bu * NT + i + 1) * 16);

        #pragma unroll 1
        for (int sub = 0; sub < 2; ++sub) {
            const float tsub  = t0v + (float)sub * hh;
            // stage-6 time fl(tsub+hh): matches reference searchsorted('right')
            const bool  swap6 = (tsub + hh >= t1v);

            // a1 = W0y*y + b0 + aclPartC   (x-broadcast round trip)
            __builtin_amdgcn_wave_barrier();
            xb[m] = y;                        // both pair-lanes: same addr, same data
            __builtin_amdgcn_wave_barrier();
            float a1v;
            {
                float xr[32];
                #pragma unroll
                for (int q = 0; q < 8; ++q) *(float4*)&xr[q * 4] = *(const float4*)&xb[q * 4];
                const v2f* xp = (const v2f*)xr;
                const v2f* wp = (const v2f*)w0r;
                v2f s0 = mkv2(b0r + aclPartC, 0.f), s1 = mkv2(0.f, 0.f);
                #pragma unroll
                for (int q = 0; q < 16; q += 2) {
                    s0 = pkfma(xp[q],     wp[q],     s0);
                    s1 = pkfma(xp[q + 1], wp[q + 1], s1);
                }
                a1v = (s0.x + s1.x) + (s0.y + s1.y);
            }

            const float h1 = fmaxf(a1v, 0.f);
            const float g1 = hh * gproj(h1);
            const float h2 = fmaxf(fmaf(0.2f, g1, a1v), 0.f);
            const float g2 = hh * gproj(h2);
            const float h3 = fmaxf(fmaf(0.075f, g1, fmaf(0.225f, g2, a1v)), 0.f);
            const float g3 = hh * gproj(h3);
            const float h4 = fmaxf(
                fmaf((float)(44.0/45.0), g1,
                fmaf((float)(-56.0/15.0), g2,
                fmaf((float)(32.0/9.0), g3, a1v))), 0.f);
            const float g4 = hh * gproj(h4);
            const float h5 = fmaxf(
                fmaf((float)(19372.0/6561.0), g1,
                fmaf((float)(-25360.0/2187.0), g2,
                fmaf((float)(64448.0/6561.0), g3,
                fmaf((float)(-212.0/729.0), g4, a1v)))), 0.f);
            const float g5 = hh * gproj(h5);
            float a6v =
                fmaf((float)(9017.0/3168.0), g1,
                fmaf((float)(-355.0/33.0), g2,
                fmaf((float)(46732.0/5247.0), g3,
                fmaf((float)(49.0/176.0), g4,
                fmaf((float)(-5103.0/18656.0), g5, a1v)))));
            a6v += swap6 ? (aclPartN - aclPartC) : 0.f;
            const float h6 = fmaxf(a6v, 0.f);

            // hacc = sum_s B_s h_s  (B2 = 0)
            float ha = (float)(35.0/384.0) * h1;
            ha = fmaf((float)(500.0/1113.0),   h3, ha);
            ha = fmaf((float)(125.0/192.0),    h4, ha);
            ha = fmaf((float)(-2187.0/6784.0), h5, ha);
            ha = fmaf((float)(11.0/84.0),      h6, ha);

            // y += hh*(W1*hacc + b1)   (hacc-broadcast round trip)
            __builtin_amdgcn_wave_barrier();
            hb[lane] = ha;
            __builtin_amdgcn_wave_barrier();
            {
                float hr[32];
                #pragma unroll
                for (int q = 0; q < 8; ++q) *(float4*)&hr[q * 4] = *(const float4*)&hb[H + q * 4];
                const v2f* hp  = (const v2f*)hr;
                const v2f* w1p = (const v2f*)w1r;
                v2f c0 = mkv2(0.f, 0.f), c1 = mkv2(0.f, 0.f);
                #pragma unroll
                for (int q = 0; q < 16; q += 2) {
                    c0 = pkfma(hp[q],     w1p[q],     c0);
                    c1 = pkfma(hp[q + 1], w1p[q + 1], c1);
                }
                float part = (c0.x + c1.x) + (c0.y + c1.y);
                part += __shfl_xor(part, 32, 64);
                y = fmaf(hh, part + b1r, y);
            }
        }
        aclPartC = aclPartN;
        store_y(y, i + 1);
    }
}

// ---------------------------------------------------------------------------
// Kernel 3: decoder, one thread per (b,t) row, IN PLACE on out. Packed fp32.
// ---------------------------------------------------------------------------
__global__ __launch_bounds__(256, 2) void dec_kernel(
    const float* __restrict__ decW0, const float* __restrict__ decb0,
    const float* __restrict__ decW1, const float* __restrict__ decb1,
    float* __restrict__ yio)
{
    __shared__ float sW0[64 * 32];   // [j][k] as stored
    __shared__ float sW1T[64 * 64];  // [j][n]
    __shared__ float sB0[64];
    __shared__ float sB1[64];
    const int tid = threadIdx.x;
    for (int i = tid; i < 64 * 32; i += 256) sW0[i] = decW0[i];
    for (int i = tid; i < 64 * 64; i += 256) { int n = i >> 6, j = i & 63; sW1T[j * 64 + n] = decW1[i]; }
    if (tid < 64) { sB0[tid] = decb0[tid]; sB1[tid] = decb1[tid]; }
    __syncthreads();

    const size_t row = (size_t)blockIdx.x * 256 + tid;
    float* rp = &yio[row * 64];

    float xr[32];
    #pragma unroll
    for (int q = 0; q < 8; ++q) *(float4*)&xr[q * 4] = *(const float4*)&rp[q * 4];

    v2f o2[32];
    #pragma unroll
    for (int n = 0; n < 32; ++n) o2[n] = mkv2(sB1[2 * n], sB1[2 * n + 1]);

    #pragma unroll 4
    for (int j = 0; j < 64; ++j) {
        v2f a0 = mkv2(sB0[j], 0.f), a1 = mkv2(0.f, 0.f);
        #pragma unroll
        for (int q = 0; q < 8; ++q) {
            const float4 wv = *(const float4*)&sW0[j * 32 + q * 4];
            a0 = pkfma(*(const v2f*)&xr[q * 4],     mkv2(wv.x, wv.y), a0);
            a1 = pkfma(*(const v2f*)&xr[q * 4 + 2], mkv2(wv.z, wv.w), a1);
        }
        const float hj = fmaxf((a0.x + a1.x) + (a0.y + a1.y), 0.f);
        const v2f h2 = mkv2(hj, hj);
        #pragma unroll
        for (int q = 0; q < 16; ++q) {
            const float4 wv = *(const float4*)&sW1T[j * 64 + q * 4];
            o2[2 * q]     = pkfma(h2, mkv2(wv.x, wv.y), o2[2 * q]);
            o2[2 * q + 1] = pkfma(h2, mkv2(wv.z, wv.w), o2[2 * q + 1]);
        }
    }

    #pragma unroll
    for (int q = 0; q < 16; ++q)
        *(float4*)&rp[q * 4] = make_float4(o2[2 * q].x, o2[2 * q].y,
                                           o2[2 * q + 1].x, o2[2 * q + 1].y);
}

extern "C" void kernel_launch(void* const* d_in, const int* in_sizes, int n_in,
                              void* d_out, int out_size, void* d_ws, size_t ws_size,
                              hipStream_t stream)
{
    const float* encW0 = (const float*)d_in[0];
    const float* encb0 = (const float*)d_in[1];
    const float* encW1 = (const float*)d_in[2];
    const float* encb1 = (const float*)d_in[3];
    const float* acW0  = (const float*)d_in[4];
    const float* acb0  = (const float*)d_in[5];
    const float* acW1  = (const float*)d_in[6];
    const float* acb1  = (const float*)d_in[7];
    const float* dynW0 = (const float*)d_in[8];
    const float* dynb0 = (const float*)d_in[9];
    const float* dynW1 = (const float*)d_in[10];
    const float* dynb1 = (const float*)d_in[11];
    const float* decW0 = (const float*)d_in[12];
    const float* decb0 = (const float*)d_in[13];
    const float* decW1 = (const float*)d_in[14];
    const float* decb1 = (const float*)d_in[15];
    const float* ob    = (const float*)d_in[16];
    const float* acs   = (const float*)d_in[17];
    const float* times = (const float*)d_in[18];
    float* out = (float*)d_out;
    float* acl = (float*)d_ws;   // NB*NT*16 floats = 16.8 MB scratch

    acl_kernel<<<(NB * NT) / 256, 256, 0, stream>>>(acs, acW0, acb0, acW1, acb1, acl);
    ode_kernel<<<NB / 4, 256, 0, stream>>>(encW0, encb0, encW1, encb1,
                                           dynW0, dynb0, dynW1, dynb1,
                                           ob, times, acl, out);
    dec_kernel<<<(NB * NT) / 256, 256, 0, stream>>>(decW0, decb0, decW1, decb1, out);
}